// Round 1
// baseline (1228.798 us; speedup 1.0000x reference)
//
#include <hip/hip_runtime.h>
#include <cstdint>
#include <cstddef>

typedef unsigned short u16;
typedef __bf16 bf16x8 __attribute__((ext_vector_type(8)));
typedef float f32x4 __attribute__((ext_vector_type(4)));

#define N_NODES 20000
#define MPAD    20096      // 157 * 128
#define E_EDGES 640000
#define K1      3000
#define K1P     3008       // 47 * 64
#define H_DIM   512
#define NW      1024       // W1|W2 fused width
#define O_DIM   256

__device__ __forceinline__ float bf2f(unsigned int hi) {
  union { unsigned int u; float f; } v; v.u = hi << 16; return v.f;
}
__device__ __forceinline__ u16 f2bf(float f) {
  union { float f; unsigned int u; } v; v.f = f;
  unsigned int u = v.u;
  return (u16)((u + 0x7fffu + ((u >> 16) & 1u)) >> 16);
}

__device__ __forceinline__ void gl2lds16(const void* g, void* l) {
  __builtin_amdgcn_global_load_lds((const __attribute__((address_space(1))) void*)g,
                                   (__attribute__((address_space(3))) void*)l, 16, 0, 0);
}

// ---------------- edge preprocessing ----------------
__global__ __launch_bounds__(256) void deg_init_k(float* degS, float* degD, int* cntS, int* cntD) {
  int i = blockIdx.x * 256 + threadIdx.x;
  if (i < N_NODES) { degS[i] = 1.0f; degD[i] = 1.0f; cntS[i] = 0; cntD[i] = 0; }
}

__global__ __launch_bounds__(256) void deg_accum_k(const int* eiS, const float* ewS,
                                                   const int* eiD, const float* ewD,
                                                   float* degS, float* degD, int* cntS, int* cntD) {
  int e = blockIdx.x * 256 + threadIdx.x;
  if (e < E_EDGES) {
    int cs = eiS[E_EDGES + e];
    atomicAdd(&degS[cs], ewS[e]);
    atomicAdd(&cntS[cs], 1);
    int cd = eiD[E_EDGES + e];
    atomicAdd(&degD[cd], ewD[e]);
    atomicAdd(&cntD[cd], 1);
  }
}

__global__ __launch_bounds__(256) void dinv_k(const float* degS, const float* degD,
                                              float* dinvS, float* dinvD) {
  int i = blockIdx.x * 256 + threadIdx.x;
  if (i < N_NODES) { dinvS[i] = rsqrtf(degS[i]); dinvD[i] = rsqrtf(degD[i]); }
}

__global__ __launch_bounds__(1024) void scan_k(const int* cntS, int* offS, int* curS,
                                               const int* cntD, int* offD, int* curD) {
  const int* cnt = blockIdx.x ? cntD : cntS;
  int* off = blockIdx.x ? offD : offS;
  int* cur = blockIdx.x ? curD : curS;
  __shared__ int sums[1024];
  const int t = threadIdx.x;
  const int CH = 20;
  int base = t * CH;
  int s = 0;
  for (int j = 0; j < CH; ++j) { int idx = base + j; if (idx < N_NODES) s += cnt[idx]; }
  sums[t] = s;
  __syncthreads();
  for (int d = 1; d < 1024; d <<= 1) {
    int v = (t >= d) ? sums[t - d] : 0;
    __syncthreads();
    sums[t] += v;
    __syncthreads();
  }
  int run = sums[t] - s;   // exclusive prefix
  for (int j = 0; j < CH; ++j) {
    int idx = base + j;
    if (idx <= N_NODES) {
      off[idx] = run; cur[idx] = run;
      if (idx < N_NODES) run += cnt[idx];
    }
  }
}

__global__ __launch_bounds__(256) void scatter_k(const int* eiS, const float* ewS, const float* dinvS,
                                                 int* curS, int* ssrcS, float* snrmS,
                                                 const int* eiD, const float* ewD, const float* dinvD,
                                                 int* curD, int* ssrcD, float* snrmD) {
  int e = blockIdx.x * 256 + threadIdx.x;
  if (e < E_EDGES) {
    {
      int r = eiS[e], c = eiS[E_EDGES + e];
      int pos = atomicAdd(&curS[c], 1);
      ssrcS[pos] = r;
      snrmS[pos] = dinvS[r] * ewS[e] * dinvS[c];
    }
    {
      int r = eiD[e], c = eiD[E_EDGES + e];
      int pos = atomicAdd(&curD[c], 1);
      ssrcD[pos] = r;
      snrmD[pos] = dinvD[r] * ewD[e] * dinvD[c];
    }
  }
}

// ---------------- conversions ----------------
// x [20000][3000] f32 -> xb [MPAD][K1P] bf16 (zero-padded).  3000 = 375*8 exactly.
__global__ __launch_bounds__(256) void conv_x_k(const float* __restrict__ x, u16* __restrict__ xb) {
  const int row = blockIdx.x;
  for (int c = threadIdx.x; c < 376; c += 256) {
    uint4 o = {0, 0, 0, 0};
    if (row < N_NODES && c < 375) {
      const float4* p = (const float4*)(x + (size_t)row * K1 + (size_t)c * 8);
      float4 v0 = p[0], v1 = p[1];
      o.x = f2bf(v0.x) | ((unsigned)f2bf(v0.y) << 16);
      o.y = f2bf(v0.z) | ((unsigned)f2bf(v0.w) << 16);
      o.z = f2bf(v1.x) | ((unsigned)f2bf(v1.y) << 16);
      o.w = f2bf(v1.z) | ((unsigned)f2bf(v1.w) << 16);
    }
    *(uint4*)(xb + (size_t)row * K1P + (size_t)c * 8) = o;
  }
}

// W1,W2 [3000][512] -> w12t [1024][3008] bf16 (transposed, padded)
__global__ __launch_bounds__(256) void conv_w12_k(const float* __restrict__ W1,
                                                  const float* __restrict__ W2,
                                                  u16* __restrict__ w12t) {
  const int n = blockIdx.x;           // 0..1023
  const float* W = (n < H_DIM) ? W1 : W2;
  const int nn = n & (H_DIM - 1);
  for (int k = threadIdx.x; k < K1P; k += 256)
    w12t[(size_t)n * K1P + k] = (k < K1) ? f2bf(W[(size_t)k * H_DIM + nn]) : (u16)0;
}

// Ws/Wd/Wf [512][256] -> [256][512] bf16
__global__ __launch_bounds__(256) void conv_wsm_k(const float* Ws, const float* Wd, const float* Wf,
                                                  u16* wst, u16* wdt, u16* wft) {
  const int n = blockIdx.x;           // 0..255
  const int which = blockIdx.y;
  const float* W = (which == 0) ? Ws : (which == 1) ? Wd : Wf;
  u16* o = (which == 0) ? wst : (which == 1) ? wdt : wft;
  for (int k = threadIdx.x; k < H_DIM; k += 256)
    o[(size_t)n * H_DIM + k] = f2bf(W[(size_t)k * O_DIM + n]);
}

// ---------------- GEMM: C[M,N] = A[M,K] * Bt[N,K]^T  (bf16 in, fp32 acc) ----------------
template <typename CT, bool BIAS>
__global__ __launch_bounds__(256) void gemm_bt(const u16* __restrict__ A, const u16* __restrict__ Bt,
                                               CT* __restrict__ C, const float* __restrict__ bias,
                                               int Mreal, int K, int ldc) {
  __shared__ alignas(16) u16 As[128 * 64];
  __shared__ alignas(16) u16 Bs[128 * 64];
  const int tid = threadIdx.x;
  const int lane = tid & 63;
  const int wv = tid >> 6;
  const int bm = blockIdx.y * 128;
  const int bn = blockIdx.x * 128;

  const int wm = (wv >> 1) << 6;
  const int wn = (wv & 1) << 6;
  const int frow = lane & 15;
  const int fk = (lane >> 4) << 3;

  // staging: round r covers rows r*32..r*32+31; lane supplies its own global addr,
  // LDS dest = wave-uniform base + lane*16B (global_load_lds constraint)
  const int srow = tid >> 3;          // 0..31
  const int skin = (tid & 7) << 3;    // 0,8,..,56
  const u16* ga = A + (size_t)(bm + srow) * K + skin;
  const u16* gb = Bt + (size_t)(bn + srow) * K + skin;
  u16* la = &As[wv * 512];
  u16* lb = &Bs[wv * 512];

  f32x4 acc[4][4] = {};

  for (int k0 = 0; k0 < K; k0 += 64) {
#pragma unroll
    for (int r = 0; r < 4; ++r) {
      gl2lds16(ga + (size_t)(r * 32) * K + k0, la + r * 2048);
      gl2lds16(gb + (size_t)(r * 32) * K + k0, lb + r * 2048);
    }
    __syncthreads();
#pragma unroll
    for (int ks = 0; ks < 64; ks += 32) {
      bf16x8 af[4], bv[4];
#pragma unroll
      for (int t = 0; t < 4; ++t) {
        af[t] = *(const bf16x8*)&As[(wm + t * 16 + frow) * 64 + ks + fk];
        bv[t] = *(const bf16x8*)&Bs[(wn + t * 16 + frow) * 64 + ks + fk];
      }
#pragma unroll
      for (int i = 0; i < 4; ++i)
#pragma unroll
        for (int j = 0; j < 4; ++j)
          acc[i][j] = __builtin_amdgcn_mfma_f32_16x16x32_bf16(af[i], bv[j], acc[i][j], 0, 0, 0);
    }
    __syncthreads();
  }

  // C/D layout (m89-verified): col = lane&15, row = (lane>>4)*4 + reg
  const int crow = (lane >> 4) << 2;
  const int ccol = lane & 15;
#pragma unroll
  for (int i = 0; i < 4; ++i) {
#pragma unroll
    for (int r = 0; r < 4; ++r) {
      int gr = bm + wm + i * 16 + crow + r;
      if (gr < Mreal) {
#pragma unroll
        for (int j = 0; j < 4; ++j) {
          int gc = bn + wn + j * 16 + ccol;
          float v = acc[i][j][r];
          if constexpr (BIAS) v += bias[gc];
          if constexpr (sizeof(CT) == 2) C[(size_t)gr * ldc + gc] = (CT)f2bf(v);
          else C[(size_t)gr * ldc + gc] = (CT)v;
        }
      }
    }
  }
}

// ---------------- aggregation layer 1: xsd[g][i][:] = relu(agg(h12 cols g*512..) + b) ----------------
__global__ __launch_bounds__(256) void agg1_k(const u16* __restrict__ h12,
                                              const int* offS, const int* srcS, const float* nrmS,
                                              const float* dinvS, const float* b1,
                                              const int* offD, const int* srcD, const float* nrmD,
                                              const float* dinvD, const float* b2,
                                              u16* __restrict__ xsd) {
  const int lane = threadIdx.x & 63;
  const int wv = threadIdx.x >> 6;
  const int i = blockIdx.x * 4 + wv;       // node (0..MPAD)
  const int g = blockIdx.y;
  if (i >= MPAD) return;
  u16* outp = xsd + ((size_t)g * MPAD + i) * H_DIM + lane * 8;
  if (i >= N_NODES) { uint4 z = {0, 0, 0, 0}; *(uint4*)outp = z; return; }

  const int* off = g ? offD : offS;
  const int* src = g ? srcD : srcS;
  const float* nrm = g ? nrmD : nrmS;
  const float* dinv = g ? dinvD : dinvS;
  const float* bias = g ? b2 : b1;
  const size_t cb = (size_t)g * H_DIM + lane * 8;

  float a[8];
  float dv = dinv[i];
  float sw = dv * dv;
  uint4 u = *(const uint4*)(h12 + (size_t)i * NW + cb);
  a[0] = sw * bf2f(u.x & 0xffff); a[1] = sw * bf2f(u.x >> 16);
  a[2] = sw * bf2f(u.y & 0xffff); a[3] = sw * bf2f(u.y >> 16);
  a[4] = sw * bf2f(u.z & 0xffff); a[5] = sw * bf2f(u.z >> 16);
  a[6] = sw * bf2f(u.w & 0xffff); a[7] = sw * bf2f(u.w >> 16);

  const int e0 = off[i], e1 = off[i + 1];
  for (int e = e0; e < e1; ++e) {
    int s = src[e];
    float w = nrm[e];
    uint4 v = *(const uint4*)(h12 + (size_t)s * NW + cb);
    a[0] += w * bf2f(v.x & 0xffff); a[1] += w * bf2f(v.x >> 16);
    a[2] += w * bf2f(v.y & 0xffff); a[3] += w * bf2f(v.y >> 16);
    a[4] += w * bf2f(v.z & 0xffff); a[5] += w * bf2f(v.z >> 16);
    a[6] += w * bf2f(v.w & 0xffff); a[7] += w * bf2f(v.w >> 16);
  }
  float4 bA = *(const float4*)(bias + lane * 8);
  float4 bB = *(const float4*)(bias + lane * 8 + 4);
  a[0] = fmaxf(a[0] + bA.x, 0.f); a[1] = fmaxf(a[1] + bA.y, 0.f);
  a[2] = fmaxf(a[2] + bA.z, 0.f); a[3] = fmaxf(a[3] + bA.w, 0.f);
  a[4] = fmaxf(a[4] + bB.x, 0.f); a[5] = fmaxf(a[5] + bB.y, 0.f);
  a[6] = fmaxf(a[6] + bB.z, 0.f); a[7] = fmaxf(a[7] + bB.w, 0.f);
  uint4 o;
  o.x = f2bf(a[0]) | ((unsigned)f2bf(a[1]) << 16);
  o.y = f2bf(a[2]) | ((unsigned)f2bf(a[3]) << 16);
  o.z = f2bf(a[4]) | ((unsigned)f2bf(a[5]) << 16);
  o.w = f2bf(a[6]) | ((unsigned)f2bf(a[7]) << 16);
  *(uint4*)outp = o;
}

// ---------------- aggregation layer 2: x_sim/x_dist fp32 -> d_out, bf16 -> xcat ----------------
__global__ __launch_bounds__(256) void agg2_k(const u16* __restrict__ hsb, const u16* __restrict__ hdb,
                                              const int* offS, const int* srcS, const float* nrmS,
                                              const float* dinvS, const float* bs,
                                              const int* offD, const int* srcD, const float* nrmD,
                                              const float* dinvD, const float* bd,
                                              float* __restrict__ outF, u16* __restrict__ xcat) {
  const int lane = threadIdx.x & 63;
  const int wv = threadIdx.x >> 6;
  const int i = blockIdx.x * 4 + wv;
  const int g = blockIdx.y;
  if (i >= MPAD) return;
  u16* oc = xcat + (size_t)i * H_DIM + (size_t)g * O_DIM + lane * 4;
  if (i >= N_NODES) { uint2 z = {0, 0}; *(uint2*)oc = z; return; }

  const u16* h = g ? hdb : hsb;
  const int* off = g ? offD : offS;
  const int* src = g ? srcD : srcS;
  const float* nrm = g ? nrmD : nrmS;
  const float* dinv = g ? dinvD : dinvS;
  const float* bias = g ? bd : bs;

  float a[4];
  float dv = dinv[i];
  float sw = dv * dv;
  uint2 u = *(const uint2*)(h + (size_t)i * O_DIM + lane * 4);
  a[0] = sw * bf2f(u.x & 0xffff); a[1] = sw * bf2f(u.x >> 16);
  a[2] = sw * bf2f(u.y & 0xffff); a[3] = sw * bf2f(u.y >> 16);

  const int e0 = off[i], e1 = off[i + 1];
  for (int e = e0; e < e1; ++e) {
    int s = src[e];
    float w = nrm[e];
    uint2 v = *(const uint2*)(h + (size_t)s * O_DIM + lane * 4);
    a[0] += w * bf2f(v.x & 0xffff); a[1] += w * bf2f(v.x >> 16);
    a[2] += w * bf2f(v.y & 0xffff); a[3] += w * bf2f(v.y >> 16);
  }
  float4 bb = *(const float4*)(bias + lane * 4);
  a[0] += bb.x; a[1] += bb.y; a[2] += bb.z; a[3] += bb.w;

  float4 fo = {a[0], a[1], a[2], a[3]};
  *(float4*)(outF + (size_t)g * N_NODES * O_DIM + (size_t)i * O_DIM + lane * 4) = fo;
  uint2 o;
  o.x = f2bf(a[0]) | ((unsigned)f2bf(a[1]) << 16);
  o.y = f2bf(a[2]) | ((unsigned)f2bf(a[3]) << 16);
  *(uint2*)oc = o;
}

// ---------------- launch ----------------
extern "C" void kernel_launch(void* const* d_in, const int* in_sizes, int n_in,
                              void* d_out, int out_size, void* d_ws, size_t ws_size,
                              hipStream_t stream) {
  const float* x = (const float*)d_in[0];
  const int* eiS = (const int*)d_in[1];
  const float* ewS = (const float*)d_in[2];
  const int* eiD = (const int*)d_in[3];
  const float* ewD = (const float*)d_in[4];
  const float* W1 = (const float*)d_in[5];
  const float* b1 = (const float*)d_in[6];
  const float* W2 = (const float*)d_in[7];
  const float* b2 = (const float*)d_in[8];
  const float* Ws = (const float*)d_in[9];
  const float* bs = (const float*)d_in[10];
  const float* Wd = (const float*)d_in[11];
  const float* bd = (const float*)d_in[12];
  const float* Wf = (const float*)d_in[13];
  const float* bf_ = (const float*)d_in[14];
  float* out = (float*)d_out;

  char* p = (char*)d_ws;
  auto alloc = [&](size_t n) -> char* { char* r = p; p += (n + 255) & ~(size_t)255; return r; };

  u16* xb    = (u16*)alloc((size_t)MPAD * K1P * 2);
  u16* w12t  = (u16*)alloc((size_t)NW * K1P * 2);
  u16* h12   = (u16*)alloc((size_t)N_NODES * NW * 2);
  u16* xsd   = (u16*)alloc((size_t)2 * MPAD * H_DIM * 2);
  u16* hsb   = (u16*)alloc((size_t)N_NODES * O_DIM * 2);
  u16* hdb   = (u16*)alloc((size_t)N_NODES * O_DIM * 2);
  u16* xcat  = (u16*)alloc((size_t)MPAD * H_DIM * 2);
  u16* wst   = (u16*)alloc((size_t)O_DIM * H_DIM * 2);
  u16* wdt   = (u16*)alloc((size_t)O_DIM * H_DIM * 2);
  u16* wft   = (u16*)alloc((size_t)O_DIM * H_DIM * 2);
  float* degS = (float*)alloc((size_t)N_NODES * 4);
  float* degD = (float*)alloc((size_t)N_NODES * 4);
  float* dinvS = (float*)alloc((size_t)N_NODES * 4);
  float* dinvD = (float*)alloc((size_t)N_NODES * 4);
  int* cntS = (int*)alloc((size_t)N_NODES * 4);
  int* cntD = (int*)alloc((size_t)N_NODES * 4);
  int* offS = (int*)alloc((size_t)(N_NODES + 1) * 4);
  int* offD = (int*)alloc((size_t)(N_NODES + 1) * 4);
  int* curS = (int*)alloc((size_t)(N_NODES + 1) * 4);
  int* curD = (int*)alloc((size_t)(N_NODES + 1) * 4);
  int* ssrcS = (int*)alloc((size_t)E_EDGES * 4);
  int* ssrcD = (int*)alloc((size_t)E_EDGES * 4);
  float* snrmS = (float*)alloc((size_t)E_EDGES * 4);
  float* snrmD = (float*)alloc((size_t)E_EDGES * 4);

  const int gN = (N_NODES + 255) / 256;     // 79
  const int gE = (E_EDGES + 255) / 256;     // 2500

  deg_init_k<<<gN, 256, 0, stream>>>(degS, degD, cntS, cntD);
  deg_accum_k<<<gE, 256, 0, stream>>>(eiS, ewS, eiD, ewD, degS, degD, cntS, cntD);
  dinv_k<<<gN, 256, 0, stream>>>(degS, degD, dinvS, dinvD);
  scan_k<<<2, 1024, 0, stream>>>(cntS, offS, curS, cntD, offD, curD);
  scatter_k<<<gE, 256, 0, stream>>>(eiS, ewS, dinvS, curS, ssrcS, snrmS,
                                    eiD, ewD, dinvD, curD, ssrcD, snrmD);

  conv_x_k<<<MPAD, 256, 0, stream>>>(x, xb);
  conv_w12_k<<<NW, 256, 0, stream>>>(W1, W2, w12t);
  conv_wsm_k<<<dim3(O_DIM, 3), 256, 0, stream>>>(Ws, Wd, Wf, wst, wdt, wft);

  // h12 = xb @ w12t^T  [20000 x 1024]
  gemm_bt<u16, false><<<dim3(8, 157), 256, 0, stream>>>(xb, w12t, h12, nullptr, N_NODES, K1P, NW);

  agg1_k<<<dim3(MPAD / 4, 2), 256, 0, stream>>>(h12, offS, ssrcS, snrmS, dinvS, b1,
                                                offD, ssrcD, snrmD, dinvD, b2, xsd);

  gemm_bt<u16, false><<<dim3(2, 157), 256, 0, stream>>>(xsd, wst, hsb, nullptr, N_NODES, H_DIM, O_DIM);
  gemm_bt<u16, false><<<dim3(2, 157), 256, 0, stream>>>(xsd + (size_t)MPAD * H_DIM, wdt, hdb, nullptr,
                                                        N_NODES, H_DIM, O_DIM);

  agg2_k<<<dim3(MPAD / 4, 2), 256, 0, stream>>>(hsb, hdb, offS, ssrcS, snrmS, dinvS, bs,
                                                offD, ssrcD, snrmD, dinvD, bd, out, xcat);

  // fused = xcat @ wft^T + bf  -> d_out[2*N*O ..]
  gemm_bt<float, true><<<dim3(2, 157), 256, 0, stream>>>(xcat, wft, out + (size_t)2 * N_NODES * O_DIM,
                                                         bf_, N_NODES, H_DIM, O_DIM);
}

// Round 2
// 1133.729 us; speedup vs baseline: 1.0839x; 1.0839x over previous
//
#include <hip/hip_runtime.h>
#include <cstdint>
#include <cstddef>

typedef unsigned short u16;
typedef __bf16 bf16x8 __attribute__((ext_vector_type(8)));
typedef float f32x4 __attribute__((ext_vector_type(4)));

#define N_NODES 20000
#define MPAD    20096      // 157 * 128
#define E_EDGES 640000
#define K1      3000
#define K1P     3008       // 47 * 64
#define H_DIM   512
#define NW      1024       // W1|W2 fused width
#define O_DIM   256

__device__ __forceinline__ float bf2f(unsigned int hi) {
  union { unsigned int u; float f; } v; v.u = hi << 16; return v.f;
}
__device__ __forceinline__ u16 f2bf(float f) {
  union { float f; unsigned int u; } v; v.f = f;
  unsigned int u = v.u;
  return (u16)((u + 0x7fffu + ((u >> 16) & 1u)) >> 16);
}

__device__ __forceinline__ void gl2lds16(const void* g, void* l) {
  __builtin_amdgcn_global_load_lds((const __attribute__((address_space(1))) void*)g,
                                   (__attribute__((address_space(3))) void*)l, 16, 0, 0);
}

// ---------------- edge preprocessing ----------------
__global__ __launch_bounds__(256) void deg_init_k(float* degS, float* degD, int* cntS, int* cntD) {
  int i = blockIdx.x * 256 + threadIdx.x;
  if (i < N_NODES) { degS[i] = 1.0f; degD[i] = 1.0f; cntS[i] = 0; cntD[i] = 0; }
}

__global__ __launch_bounds__(256) void deg_accum_k(const int* eiS, const float* ewS,
                                                   const int* eiD, const float* ewD,
                                                   float* degS, float* degD, int* cntS, int* cntD) {
  int e = blockIdx.x * 256 + threadIdx.x;
  if (e < E_EDGES) {
    int cs = eiS[E_EDGES + e];
    atomicAdd(&degS[cs], ewS[e]);
    atomicAdd(&cntS[cs], 1);
    int cd = eiD[E_EDGES + e];
    atomicAdd(&degD[cd], ewD[e]);
    atomicAdd(&cntD[cd], 1);
  }
}

__global__ __launch_bounds__(256) void dinv_k(const float* degS, const float* degD,
                                              float* dinvS, float* dinvD) {
  int i = blockIdx.x * 256 + threadIdx.x;
  if (i < N_NODES) { dinvS[i] = rsqrtf(degS[i]); dinvD[i] = rsqrtf(degD[i]); }
}

__global__ __launch_bounds__(1024) void scan_k(const int* cntS, int* offS, int* curS,
                                               const int* cntD, int* offD, int* curD) {
  const int* cnt = blockIdx.x ? cntD : cntS;
  int* off = blockIdx.x ? offD : offS;
  int* cur = blockIdx.x ? curD : curS;
  __shared__ int sums[1024];
  const int t = threadIdx.x;
  const int CH = 20;
  int base = t * CH;
  int s = 0;
  for (int j = 0; j < CH; ++j) { int idx = base + j; if (idx < N_NODES) s += cnt[idx]; }
  sums[t] = s;
  __syncthreads();
  for (int d = 1; d < 1024; d <<= 1) {
    int v = (t >= d) ? sums[t - d] : 0;
    __syncthreads();
    sums[t] += v;
    __syncthreads();
  }
  int run = sums[t] - s;   // exclusive prefix
  for (int j = 0; j < CH; ++j) {
    int idx = base + j;
    if (idx <= N_NODES) {
      off[idx] = run; cur[idx] = run;
      if (idx < N_NODES) run += cnt[idx];
    }
  }
}

__global__ __launch_bounds__(256) void scatter_k(const int* eiS, const float* ewS, const float* dinvS,
                                                 int* curS, int* ssrcS, float* snrmS,
                                                 const int* eiD, const float* ewD, const float* dinvD,
                                                 int* curD, int* ssrcD, float* snrmD) {
  int e = blockIdx.x * 256 + threadIdx.x;
  if (e < E_EDGES) {
    {
      int r = eiS[e], c = eiS[E_EDGES + e];
      int pos = atomicAdd(&curS[c], 1);
      ssrcS[pos] = r;
      snrmS[pos] = dinvS[r] * ewS[e] * dinvS[c];
    }
    {
      int r = eiD[e], c = eiD[E_EDGES + e];
      int pos = atomicAdd(&curD[c], 1);
      ssrcD[pos] = r;
      snrmD[pos] = dinvD[r] * ewD[e] * dinvD[c];
    }
  }
}

// ---------------- conversions ----------------
// x [20000][3000] f32 -> xb [MPAD][K1P] bf16 (zero-padded).  3000 = 375*8 exactly.
__global__ __launch_bounds__(256) void conv_x_k(const float* __restrict__ x, u16* __restrict__ xb) {
  const int row = blockIdx.x;
  for (int c = threadIdx.x; c < 376; c += 256) {
    uint4 o = {0, 0, 0, 0};
    if (row < N_NODES && c < 375) {
      const float4* p = (const float4*)(x + (size_t)row * K1 + (size_t)c * 8);
      float4 v0 = p[0], v1 = p[1];
      o.x = f2bf(v0.x) | ((unsigned)f2bf(v0.y) << 16);
      o.y = f2bf(v0.z) | ((unsigned)f2bf(v0.w) << 16);
      o.z = f2bf(v1.x) | ((unsigned)f2bf(v1.y) << 16);
      o.w = f2bf(v1.z) | ((unsigned)f2bf(v1.w) << 16);
    }
    *(uint4*)(xb + (size_t)row * K1P + (size_t)c * 8) = o;
  }
}

// W1,W2 [3000][512] -> w12t [1024][3008] bf16 (transposed, padded), LDS-tiled 64x64
__global__ __launch_bounds__(256) void conv_w12_k(const float* __restrict__ W1,
                                                  const float* __restrict__ W2,
                                                  u16* __restrict__ w12t) {
  __shared__ float t[64][65];
  const int kb = blockIdx.x;           // 0..46
  const int nb = blockIdx.y;           // 0..15
  const int n0 = nb * 64;
  const float* W = (n0 < H_DIM) ? W1 : W2;
  const int nn0 = n0 & (H_DIM - 1);
  const int k0 = kb * 64;
  const int tc = threadIdx.x & 63;
  const int tr4 = threadIdx.x >> 6;    // 0..3
#pragma unroll
  for (int rr = 0; rr < 16; ++rr) {
    int r = tr4 * 16 + rr;
    int k = k0 + r;
    t[r][tc] = (k < K1) ? W[(size_t)k * H_DIM + nn0 + tc] : 0.f;
  }
  __syncthreads();
#pragma unroll
  for (int rr = 0; rr < 16; ++rr) {
    int n = tr4 * 16 + rr;
    w12t[(size_t)(n0 + n) * K1P + k0 + tc] = f2bf(t[tc][n]);
  }
}

// Ws/Wd/Wf [512][256] -> [256][512] bf16, LDS-tiled 64x64
__global__ __launch_bounds__(256) void conv_wsm_k(const float* Ws, const float* Wd, const float* Wf,
                                                  u16* wst, u16* wdt, u16* wft) {
  __shared__ float t[64][65];
  const int which = blockIdx.z;
  const float* W = (which == 0) ? Ws : (which == 1) ? Wd : Wf;
  u16* o = (which == 0) ? wst : (which == 1) ? wdt : wft;
  const int k0 = blockIdx.x * 64;      // 0..448
  const int n0 = blockIdx.y * 64;      // 0..192
  const int tc = threadIdx.x & 63;
  const int tr4 = threadIdx.x >> 6;
#pragma unroll
  for (int rr = 0; rr < 16; ++rr) {
    int r = tr4 * 16 + rr;
    t[r][tc] = W[(size_t)(k0 + r) * O_DIM + n0 + tc];
  }
  __syncthreads();
#pragma unroll
  for (int rr = 0; rr < 16; ++rr) {
    int n = tr4 * 16 + rr;
    o[(size_t)(n0 + n) * H_DIM + k0 + tc] = f2bf(t[tc][n]);
  }
}

// ---------------- GEMM: C[M,N] = A[M,K] * Bt[N,K]^T  (bf16 in, fp32 acc) ----------------
// LDS layout: row-major [128][64] u16 with XOR granule swizzle: physical 16B-granule p of
// row r holds logical granule p ^ (r&7).  Staging picks global granule (tid&7)^((tid>>3)&7)
// so the wave-uniform global_load_lds dest (base + lane*16B) lands each granule at its
// swizzled position.  Fragment ds_read_b128 then hits 8 distinct bank-quads per 8-lane
// phase group -> conflict-free (was 4.5e7 SQ_LDS_BANK_CONFLICT with the identity layout).
template <typename CT, bool BIAS>
__global__ __launch_bounds__(256) void gemm_bt(const u16* __restrict__ A, const u16* __restrict__ Bt,
                                               CT* __restrict__ C, const float* __restrict__ bias,
                                               int Mreal, int K, int ldc) {
  __shared__ alignas(16) u16 As[128 * 64];
  __shared__ alignas(16) u16 Bs[128 * 64];
  const int tid = threadIdx.x;
  const int lane = tid & 63;
  const int wv = tid >> 6;
  const int bm = blockIdx.y * 128;
  const int bn = blockIdx.x * 128;

  const int wm = (wv >> 1) << 6;
  const int wn = (wv & 1) << 6;
  const int frow = lane & 15;
  const int q = lane >> 4;             // logical granule base (0..3)
  const int r7 = lane & 7;             // row&7 for all fragment rows this lane touches

  // staging: lane supplies swizzled global granule, LDS dest = base + lane*16B
  const int srow = tid >> 3;           // 0..31
  const int sgr = ((tid & 7) ^ ((tid >> 3) & 7)) << 3;   // swizzled granule * 8 u16
  const u16* ga = A + (size_t)(bm + srow) * K + sgr;
  const u16* gb = Bt + (size_t)(bn + srow) * K + sgr;
  u16* la = &As[wv * 512];
  u16* lb = &Bs[wv * 512];

  f32x4 acc[4][4] = {};

  for (int k0 = 0; k0 < K; k0 += 64) {
#pragma unroll
    for (int r = 0; r < 4; ++r) {
      gl2lds16(ga + (size_t)(r * 32) * K + k0, la + r * 2048);
      gl2lds16(gb + (size_t)(r * 32) * K + k0, lb + r * 2048);
    }
    __syncthreads();
#pragma unroll
    for (int ks = 0; ks < 64; ks += 32) {
      const int p = (((q + (ks >> 3)) ^ r7) << 3);   // physical u16 offset within row
      bf16x8 af[4], bv[4];
#pragma unroll
      for (int t = 0; t < 4; ++t) {
        af[t] = *(const bf16x8*)&As[(wm + t * 16 + frow) * 64 + p];
        bv[t] = *(const bf16x8*)&Bs[(wn + t * 16 + frow) * 64 + p];
      }
#pragma unroll
      for (int i = 0; i < 4; ++i)
#pragma unroll
        for (int j = 0; j < 4; ++j)
          acc[i][j] = __builtin_amdgcn_mfma_f32_16x16x32_bf16(af[i], bv[j], acc[i][j], 0, 0, 0);
    }
    __syncthreads();
  }

  // C/D layout (m89-verified): col = lane&15, row = (lane>>4)*4 + reg
  const int crow = (lane >> 4) << 2;
  const int ccol = lane & 15;
#pragma unroll
  for (int i = 0; i < 4; ++i) {
#pragma unroll
    for (int r = 0; r < 4; ++r) {
      int gr = bm + wm + i * 16 + crow + r;
      if (gr < Mreal) {
#pragma unroll
        for (int j = 0; j < 4; ++j) {
          int gc = bn + wn + j * 16 + ccol;
          float v = acc[i][j][r];
          if constexpr (BIAS) v += bias[gc];
          if constexpr (sizeof(CT) == 2) C[(size_t)gr * ldc + gc] = (CT)f2bf(v);
          else C[(size_t)gr * ldc + gc] = (CT)v;
        }
      }
    }
  }
}

// ---------------- aggregation layer 1 ----------------
__global__ __launch_bounds__(256) void agg1_k(const u16* __restrict__ h12,
                                              const int* offS, const int* srcS, const float* nrmS,
                                              const float* dinvS, const float* b1,
                                              const int* offD, const int* srcD, const float* nrmD,
                                              const float* dinvD, const float* b2,
                                              u16* __restrict__ xsd) {
  const int lane = threadIdx.x & 63;
  const int wv = threadIdx.x >> 6;
  const int i = blockIdx.x * 4 + wv;       // node (0..MPAD)
  const int g = blockIdx.y;
  if (i >= MPAD) return;
  u16* outp = xsd + ((size_t)g * MPAD + i) * H_DIM + lane * 8;
  if (i >= N_NODES) { uint4 z = {0, 0, 0, 0}; *(uint4*)outp = z; return; }

  const int* off = g ? offD : offS;
  const int* src = g ? srcD : srcS;
  const float* nrm = g ? nrmD : nrmS;
  const float* dinv = g ? dinvD : dinvS;
  const float* bias = g ? b2 : b1;
  const size_t cb = (size_t)g * H_DIM + lane * 8;

  float a[8];
  float dv = dinv[i];
  float sw = dv * dv;
  uint4 u = *(const uint4*)(h12 + (size_t)i * NW + cb);
  a[0] = sw * bf2f(u.x & 0xffff); a[1] = sw * bf2f(u.x >> 16);
  a[2] = sw * bf2f(u.y & 0xffff); a[3] = sw * bf2f(u.y >> 16);
  a[4] = sw * bf2f(u.z & 0xffff); a[5] = sw * bf2f(u.z >> 16);
  a[6] = sw * bf2f(u.w & 0xffff); a[7] = sw * bf2f(u.w >> 16);

  const int e0 = off[i], e1 = off[i + 1];
  for (int e = e0; e < e1; ++e) {
    int s = src[e];
    float w = nrm[e];
    uint4 v = *(const uint4*)(h12 + (size_t)s * NW + cb);
    a[0] += w * bf2f(v.x & 0xffff); a[1] += w * bf2f(v.x >> 16);
    a[2] += w * bf2f(v.y & 0xffff); a[3] += w * bf2f(v.y >> 16);
    a[4] += w * bf2f(v.z & 0xffff); a[5] += w * bf2f(v.z >> 16);
    a[6] += w * bf2f(v.w & 0xffff); a[7] += w * bf2f(v.w >> 16);
  }
  float4 bA = *(const float4*)(bias + lane * 8);
  float4 bB = *(const float4*)(bias + lane * 8 + 4);
  a[0] = fmaxf(a[0] + bA.x, 0.f); a[1] = fmaxf(a[1] + bA.y, 0.f);
  a[2] = fmaxf(a[2] + bA.z, 0.f); a[3] = fmaxf(a[3] + bA.w, 0.f);
  a[4] = fmaxf(a[4] + bB.x, 0.f); a[5] = fmaxf(a[5] + bB.y, 0.f);
  a[6] = fmaxf(a[6] + bB.z, 0.f); a[7] = fmaxf(a[7] + bB.w, 0.f);
  uint4 o;
  o.x = f2bf(a[0]) | ((unsigned)f2bf(a[1]) << 16);
  o.y = f2bf(a[2]) | ((unsigned)f2bf(a[3]) << 16);
  o.z = f2bf(a[4]) | ((unsigned)f2bf(a[5]) << 16);
  o.w = f2bf(a[6]) | ((unsigned)f2bf(a[7]) << 16);
  *(uint4*)outp = o;
}

// ---------------- aggregation layer 2 ----------------
__global__ __launch_bounds__(256) void agg2_k(const u16* __restrict__ hsb, const u16* __restrict__ hdb,
                                              const int* offS, const int* srcS, const float* nrmS,
                                              const float* dinvS, const float* bs,
                                              const int* offD, const int* srcD, const float* nrmD,
                                              const float* dinvD, const float* bd,
                                              float* __restrict__ outF, u16* __restrict__ xcat) {
  const int lane = threadIdx.x & 63;
  const int wv = threadIdx.x >> 6;
  const int i = blockIdx.x * 4 + wv;
  const int g = blockIdx.y;
  if (i >= MPAD) return;
  u16* oc = xcat + (size_t)i * H_DIM + (size_t)g * O_DIM + lane * 4;
  if (i >= N_NODES) { uint2 z = {0, 0}; *(uint2*)oc = z; return; }

  const u16* h = g ? hdb : hsb;
  const int* off = g ? offD : offS;
  const int* src = g ? srcD : srcS;
  const float* nrm = g ? nrmD : nrmS;
  const float* dinv = g ? dinvD : dinvS;
  const float* bias = g ? bd : bs;

  float a[4];
  float dv = dinv[i];
  float sw = dv * dv;
  uint2 u = *(const uint2*)(h + (size_t)i * O_DIM + lane * 4);
  a[0] = sw * bf2f(u.x & 0xffff); a[1] = sw * bf2f(u.x >> 16);
  a[2] = sw * bf2f(u.y & 0xffff); a[3] = sw * bf2f(u.y >> 16);

  const int e0 = off[i], e1 = off[i + 1];
  for (int e = e0; e < e1; ++e) {
    int s = src[e];
    float w = nrm[e];
    uint2 v = *(const uint2*)(h + (size_t)s * O_DIM + lane * 4);
    a[0] += w * bf2f(v.x & 0xffff); a[1] += w * bf2f(v.x >> 16);
    a[2] += w * bf2f(v.y & 0xffff); a[3] += w * bf2f(v.y >> 16);
  }
  float4 bb = *(const float4*)(bias + lane * 4);
  a[0] += bb.x; a[1] += bb.y; a[2] += bb.z; a[3] += bb.w;

  float4 fo = {a[0], a[1], a[2], a[3]};
  *(float4*)(outF + (size_t)g * N_NODES * O_DIM + (size_t)i * O_DIM + lane * 4) = fo;
  uint2 o;
  o.x = f2bf(a[0]) | ((unsigned)f2bf(a[1]) << 16);
  o.y = f2bf(a[2]) | ((unsigned)f2bf(a[3]) << 16);
  *(uint2*)oc = o;
}

// ---------------- launch ----------------
extern "C" void kernel_launch(void* const* d_in, const int* in_sizes, int n_in,
                              void* d_out, int out_size, void* d_ws, size_t ws_size,
                              hipStream_t stream) {
  const float* x = (const float*)d_in[0];
  const int* eiS = (const int*)d_in[1];
  const float* ewS = (const float*)d_in[2];
  const int* eiD = (const int*)d_in[3];
  const float* ewD = (const float*)d_in[4];
  const float* W1 = (const float*)d_in[5];
  const float* b1 = (const float*)d_in[6];
  const float* W2 = (const float*)d_in[7];
  const float* b2 = (const float*)d_in[8];
  const float* Ws = (const float*)d_in[9];
  const float* bs = (const float*)d_in[10];
  const float* Wd = (const float*)d_in[11];
  const float* bd = (const float*)d_in[12];
  const float* Wf = (const float*)d_in[13];
  const float* bf_ = (const float*)d_in[14];
  float* out = (float*)d_out;

  char* p = (char*)d_ws;
  auto alloc = [&](size_t n) -> char* { char* r = p; p += (n + 255) & ~(size_t)255; return r; };

  u16* xb    = (u16*)alloc((size_t)MPAD * K1P * 2);
  u16* w12t  = (u16*)alloc((size_t)NW * K1P * 2);
  u16* h12   = (u16*)alloc((size_t)N_NODES * NW * 2);
  u16* xsd   = (u16*)alloc((size_t)2 * MPAD * H_DIM * 2);
  u16* hsb   = (u16*)alloc((size_t)N_NODES * O_DIM * 2);
  u16* hdb   = (u16*)alloc((size_t)N_NODES * O_DIM * 2);
  u16* xcat  = (u16*)alloc((size_t)MPAD * H_DIM * 2);
  u16* wst   = (u16*)alloc((size_t)O_DIM * H_DIM * 2);
  u16* wdt   = (u16*)alloc((size_t)O_DIM * H_DIM * 2);
  u16* wft   = (u16*)alloc((size_t)O_DIM * H_DIM * 2);
  float* degS = (float*)alloc((size_t)N_NODES * 4);
  float* degD = (float*)alloc((size_t)N_NODES * 4);
  float* dinvS = (float*)alloc((size_t)N_NODES * 4);
  float* dinvD = (float*)alloc((size_t)N_NODES * 4);
  int* cntS = (int*)alloc((size_t)N_NODES * 4);
  int* cntD = (int*)alloc((size_t)N_NODES * 4);
  int* offS = (int*)alloc((size_t)(N_NODES + 1) * 4);
  int* offD = (int*)alloc((size_t)(N_NODES + 1) * 4);
  int* curS = (int*)alloc((size_t)(N_NODES + 1) * 4);
  int* curD = (int*)alloc((size_t)(N_NODES + 1) * 4);
  int* ssrcS = (int*)alloc((size_t)E_EDGES * 4);
  int* ssrcD = (int*)alloc((size_t)E_EDGES * 4);
  float* snrmS = (float*)alloc((size_t)E_EDGES * 4);
  float* snrmD = (float*)alloc((size_t)E_EDGES * 4);

  const int gN = (N_NODES + 255) / 256;     // 79
  const int gE = (E_EDGES + 255) / 256;     // 2500

  deg_init_k<<<gN, 256, 0, stream>>>(degS, degD, cntS, cntD);
  deg_accum_k<<<gE, 256, 0, stream>>>(eiS, ewS, eiD, ewD, degS, degD, cntS, cntD);
  dinv_k<<<gN, 256, 0, stream>>>(degS, degD, dinvS, dinvD);
  scan_k<<<2, 1024, 0, stream>>>(cntS, offS, curS, cntD, offD, curD);
  scatter_k<<<gE, 256, 0, stream>>>(eiS, ewS, dinvS, curS, ssrcS, snrmS,
                                    eiD, ewD, dinvD, curD, ssrcD, snrmD);

  conv_x_k<<<MPAD, 256, 0, stream>>>(x, xb);
  conv_w12_k<<<dim3(47, 16), 256, 0, stream>>>(W1, W2, w12t);
  conv_wsm_k<<<dim3(8, 4, 3), 256, 0, stream>>>(Ws, Wd, Wf, wst, wdt, wft);

  // h12 = xb @ w12t^T  [20000 x 1024]
  gemm_bt<u16, false><<<dim3(8, 157), 256, 0, stream>>>(xb, w12t, h12, nullptr, N_NODES, K1P, NW);

  agg1_k<<<dim3(MPAD / 4, 2), 256, 0, stream>>>(h12, offS, ssrcS, snrmS, dinvS, b1,
                                                offD, ssrcD, snrmD, dinvD, b2, xsd);

  gemm_bt<u16, false><<<dim3(2, 157), 256, 0, stream>>>(xsd, wst, hsb, nullptr, N_NODES, H_DIM, O_DIM);
  gemm_bt<u16, false><<<dim3(2, 157), 256, 0, stream>>>(xsd + (size_t)MPAD * H_DIM, wdt, hdb, nullptr,
                                                        N_NODES, H_DIM, O_DIM);

  agg2_k<<<dim3(MPAD / 4, 2), 256, 0, stream>>>(hsb, hdb, offS, ssrcS, snrmS, dinvS, bs,
                                                offD, ssrcD, snrmD, dinvD, bd, out, xcat);

  // fused = xcat @ wft^T + bf  -> d_out[2*N*O ..]
  gemm_bt<float, true><<<dim3(2, 157), 256, 0, stream>>>(xcat, wft, out + (size_t)2 * N_NODES * O_DIM,
                                                         bf_, N_NODES, H_DIM, O_DIM);
}